// Round 5
// baseline (445.374 us; speedup 1.0000x reference)
//
#include <hip/hip_runtime.h>
#include <cstdint>

// Problem constants (fixed by reference setup_inputs):
//   N = 200000, M = 64, D = 256, K = 3
#define D_DIM 256
#define M_DIM 64
#define K_TOP 3

typedef unsigned long long u64;
typedef int   v4i __attribute__((ext_vector_type(4)));
typedef float v4f __attribute__((ext_vector_type(4)));

// ---------------------------------------------------------------------------
// Session facts (R0-R4 measured):
//  * dur_us = ~241 us harness poison fills (2 x 819.2 MB @ ~6.8 TB/s, ~121 us
//    each, always the top-5) + our two kernels (each <120.4 us, NEVER visible
//    in top-5 -> we have never seen their counters).
//  * Inputs L3-resident across iterations (R2 probe: hbm_bytes 7.3 MB/disp).
//  * Fusion + sw grid barrier: LOSS (427.9). Cooperative launch: hung.
//  * Branchless k2 (R3): neutral (337.16). nt+batched k1 loads (R4): WIN
//    (337.2 -> 322.9). Persistent k1/W-preload (prior session): neutral.
//  * Rejected on correctness: fast-exp / rank-by-x shortcuts (exp-collision
//    ties vs jax.lax.top_k lower-index rule -> index-magnitude errors).
//
// R5 = DIAGNOSTIC ROUND (intentional dur_us regression, revert next round):
// run each kernel body REPS=3 times per dispatch (idempotent; asm memory
// barrier per rep defeats cross-rep CSE). Both dispatches then exceed the
// ~121 us fill duration and surface in rocprof's top-5 WITH counters:
//  * k1 hbm_gbps high  -> nt loads bypass L3, nf comes from HBM each rep.
//  * k1 hbm_gbps ~0    -> L3-fed; remaining time is issue/latency.
//  * k2 occupancy/VALUBusy split: gather-latency-bound vs VALU(exp)-bound.
// Math/mapping/grid byte-identical to the verified R4 kernel.
// ---------------------------------------------------------------------------

// Kernel 1: per-node dual dot product. 4 rows per wave, 16 lanes per row.
// Lane loads 4x float4 (64B of the 1KB row), nontemporal. W re-read per wave
// is an L1 hit. Plain stores keep s_self/s_all L2/L3-resident for k2.
__global__ __launch_bounds__(256) void ns_scores_kernel(
    const float* __restrict__ nf,      // (N, 256)
    const float* __restrict__ W,       // (512,)
    const float* __restrict__ b,       // (1,)
    float* __restrict__ s_self,        // (N,)
    float* __restrict__ s_all,         // (N,)
    int N, int reps)
{
    const int wave = (blockIdx.x * blockDim.x + threadIdx.x) >> 6;
    const int lane = threadIdx.x & 63;
    const int sub  = lane >> 4;        // row slot within wave
    const int p    = lane & 15;        // lane within 16-lane team
    const int row  = wave * 4 + sub;
    if (row >= N) return;

    const v4f* __restrict__ vrow = (const v4f*)(nf + (size_t)row * D_DIM);
    const v4f* __restrict__ wa4  = (const v4f*)W;
    const v4f* __restrict__ wb4  = (const v4f*)(W + D_DIM);

    for (int r = 0; r < reps; ++r) {
        asm volatile("" ::: "memory");   // force real re-execution per rep

        v4f v[4];
        #pragma unroll
        for (int i = 0; i < 4; ++i)
            v[i] = __builtin_nontemporal_load(vrow + (i * 16 + p));

        float sa = 0.0f, sb = 0.0f;
        #pragma unroll
        for (int i = 0; i < 4; ++i) {
            const v4f a = wa4[i * 16 + p];
            const v4f c = wb4[i * 16 + p];
            sa += v[i].x * a.x + v[i].y * a.y + v[i].z * a.z + v[i].w * a.w;
            sb += v[i].x * c.x + v[i].y * c.y + v[i].z * c.z + v[i].w * c.w;
        }
        #pragma unroll
        for (int off = 8; off > 0; off >>= 1) {
            sa += __shfl_xor(sa, off);
            sb += __shfl_xor(sb, off);
        }
        if (p == 0) {
            s_self[row] = sa + b[0];     // identical value every rep
            s_all[row]  = sb;
        }
    }
}

// Kernel 2: per-node score + top-3 (verified R3/R4 math, wrapped in reps).
__global__ __launch_bounds__(256) void ns_topk_kernel(
    const int* __restrict__ neighbors, // (N, 64) int32
    const int* __restrict__ counts,    // (N,)    int32
    const float* __restrict__ s_self,  // (N,)
    const float* __restrict__ s_all,   // (N,)
    float* __restrict__ out_vals,      // (N, 3)
    float* __restrict__ out_idx,       // (N, 3)  indices as float
    int N, int reps)
{
    const int wave = (blockIdx.x * blockDim.x + threadIdx.x) >> 6;
    const int lane = threadIdx.x & 63;
    const int sub  = lane >> 4;
    const int p    = lane & 15;
    const int row  = wave * 4 + sub;
    if (row >= N) return;

    for (int r = 0; r < reps; ++r) {
        asm volatile("" ::: "memory");   // force real re-execution per rep

        const int   cnt = counts[row];   // uniform in team -> broadcast line
        const float ss  = s_self[row];

        v4i nb = (v4i){0, 0, 0, 0};
        if (p * 4 < cnt) {               // skip fully-masked int4s entirely
            nb = __builtin_nontemporal_load(
                (const v4i*)(neighbors + (size_t)row * M_DIM) + p);
        }

        const int nbs[4] = { nb.x, nb.y, nb.z, nb.w };
        u64 key[4];
        #pragma unroll
        for (int e = 0; e < 4; ++e) {
            const int j = p * 4 + e;
            const float x  = ss + s_all[nbs[e]];       // L2-resident gather
            const float lr = (x >= 0.0f) ? x : 0.01f * x;
            const float sc = expf(lr);                 // finite for all inputs
            const float score = (j < cnt) ? sc : 0.0f; // select, not branch
            key[e] = ((u64)__float_as_uint(score) << 32) | (u64)(63 - j);
        }

        float vals[K_TOP];
        int   idxs[K_TOP];

        #pragma unroll
        for (int k = 0; k < K_TOP; ++k) {
            u64 m = key[0];
            if (key[1] > m) m = key[1];
            if (key[2] > m) m = key[2];
            if (key[3] > m) m = key[3];
            #pragma unroll
            for (int off = 8; off > 0; off >>= 1) {
                const u64 o = __shfl_xor(m, off);
                if (o > m) m = o;
            }
            const int jwin = 63 - (int)(m & 0x3F);
            vals[k] = __uint_as_float((unsigned)(m >> 32));

            const int ew = jwin & 3;     // element within owner's int4
            const int pw = jwin >> 2;    // owner lane within team
            const int cand = (ew == 0) ? nbs[0] : (ew == 1) ? nbs[1]
                           : (ew == 2) ? nbs[2] : nbs[3];
            idxs[k] = __shfl(cand, (sub << 4) | pw);  // owner active (jwin<cnt)

            if (p == pw) {               // owner knocks out winning element
                const u64 dead = (u64)(63 - jwin);
                if      (ew == 0) key[0] = dead;
                else if (ew == 1) key[1] = dead;
                else if (ew == 2) key[2] = dead;
                else              key[3] = dead;
            }
        }

        if (p == 0) {
            const size_t base = (size_t)row * K_TOP;
            #pragma unroll
            for (int k = 0; k < K_TOP; ++k) {
                out_vals[base + k] = vals[k];          // identical every rep
                out_idx [base + k] = (float)idxs[k];
            }
        }
    }
}

extern "C" void kernel_launch(void* const* d_in, const int* in_sizes, int n_in,
                              void* d_out, int out_size, void* d_ws, size_t ws_size,
                              hipStream_t stream)
{
    const float* nf        = (const float*)d_in[0];   // (N, 256)
    const int*   neighbors = (const int*)  d_in[1];   // (N, 64)
    const int*   counts    = (const int*)  d_in[2];   // (N,)
    const float* W         = (const float*)d_in[3];   // (512,)
    const float* b         = (const float*)d_in[4];   // (1,)

    const int N = in_sizes[2];

    float* s_self = (float*)d_ws;                     // N floats
    float* s_all  = s_self + N;                       // N floats

    float* out_vals = (float*)d_out;                  // N*3
    float* out_idx  = out_vals + (size_t)N * K_TOP;   // N*3 (indices as float)

    const int threads = 256;                          // 4 waves -> 16 rows/block
    const int rowsPerBlock = (threads / 64) * 4;
    const int blocks = (N + rowsPerBlock - 1) / rowsPerBlock;

    const int REPS = 3;   // DIAGNOSTIC: amplify both kernels past the ~121 us
                          // fill bar so they surface in rocprof top-5.

    ns_scores_kernel<<<blocks, threads, 0, stream>>>(nf, W, b, s_self, s_all,
                                                     N, REPS);
    ns_topk_kernel<<<blocks, threads, 0, stream>>>(neighbors, counts, s_self,
                                                   s_all, out_vals, out_idx,
                                                   N, REPS);
}

// Round 6
// 322.227 us; speedup vs baseline: 1.3822x; 1.3822x over previous
//
#include <hip/hip_runtime.h>
#include <cstdint>

// Problem constants (fixed by reference setup_inputs):
//   N = 200000, M = 64, D = 256, K = 3
#define D_DIM 256
#define M_DIM 64
#define K_TOP 3

typedef unsigned long long u64;
typedef int   v4i __attribute__((ext_vector_type(4)));
typedef float v4f __attribute__((ext_vector_type(4)));

// ---------------------------------------------------------------------------
// Session accounting (R0-R5 measured), for the record:
//  * dur_us(322.9 best) = ~241 us harness poison fills (2 x 819.2 MB @
//    ~6.8 TB/s, the permanent top-5) + ~61 us kernel pair + ~20 us gaps.
//  * R5 reps-diagnostic: marginal rep-pair = 61.2 us; k1 < 40 us, k2 < 40 us
//    single-shot (3x of each still below the 120 us fill bar).
//  * Inputs (226 MB) are L3-resident across iterations (R2 probe: hbm_bytes
//    7.3 MB/dispatch, 0.2% of peak). Kernels are L3/L2-bound, not HBM-bound.
//  * Floor arithmetic: k1 ~15-20 us (205 MB nf from L3), k2 ~20-30 us
//    (6.6M random L2 line-gathers + 12.8M exp/pack/sort VALU). Pair at 61 us
//    is within ~1.3-1.5x of the optimistic cache roofline; addressable slack
//    <6% of dur_us.
//  * Measured levers: fusion+sw-barrier LOSS (-107 us); cooperative launch
//    HANG; persistent k1/W-preload NEUTRAL; branchless k2 NEUTRAL;
//    nt+batched k1 loads WIN (+14.3 us, kept); fast-exp / rank-by-x
//    REJECTED (tie-break vs jax.lax.top_k lower-index rule at absmax ==
//    threshold).
// This file = the verified best (R4) kernel, diagnostic reps removed.
// ---------------------------------------------------------------------------

// Kernel 1: per-node dual dot product. 4 rows per wave, 16 lanes per row.
// Lane loads 4x float4 (64B of the 1KB row), nontemporal (read-once stream;
// no L1/L2 write-allocate churn -> the R4 +14 us win). W re-read per wave is
// an L1 hit. Plain stores keep s_self/s_all L2/L3-resident for k2.
__global__ __launch_bounds__(256) void ns_scores_kernel(
    const float* __restrict__ nf,      // (N, 256)
    const float* __restrict__ W,       // (512,)
    const float* __restrict__ b,       // (1,)
    float* __restrict__ s_self,        // (N,)
    float* __restrict__ s_all,         // (N,)
    int N)
{
    const int wave = (blockIdx.x * blockDim.x + threadIdx.x) >> 6;
    const int lane = threadIdx.x & 63;
    const int sub  = lane >> 4;        // row slot within wave
    const int p    = lane & 15;        // lane within 16-lane team
    const int row  = wave * 4 + sub;
    if (row >= N) return;

    const v4f* __restrict__ vrow = (const v4f*)(nf + (size_t)row * D_DIM);
    const v4f* __restrict__ wa4  = (const v4f*)W;
    const v4f* __restrict__ wb4  = (const v4f*)(W + D_DIM);

    // Batch the 4 streaming loads first (max memory-level parallelism),
    // then run the FMA chains.
    v4f v[4];
    #pragma unroll
    for (int i = 0; i < 4; ++i)
        v[i] = __builtin_nontemporal_load(vrow + (i * 16 + p));

    float sa = 0.0f, sb = 0.0f;
    #pragma unroll
    for (int i = 0; i < 4; ++i) {
        const v4f a = wa4[i * 16 + p];
        const v4f c = wb4[i * 16 + p];
        sa += v[i].x * a.x + v[i].y * a.y + v[i].z * a.z + v[i].w * a.w;
        sb += v[i].x * c.x + v[i].y * c.y + v[i].z * c.z + v[i].w * c.w;
    }
    #pragma unroll
    for (int off = 8; off > 0; off >>= 1) {
        sa += __shfl_xor(sa, off);
        sb += __shfl_xor(sb, off);
    }
    if (p == 0) {
        s_self[row] = sa + b[0];
        s_all[row]  = sb;
    }
}

// Kernel 2: per-node score + top-3. 4 rows per wave; lane p owns neighbors
// 4p..4p+3 (one int4). counts ~ U[3,63] -> guard the int4 LOAD by 4p < cnt
// (masked lanes issue no memory request, ~26 MB neighbor traffic). Neighbor
// stream nontemporal. Branchless gather: nbs[e] always in-bounds (0 for
// skipped int4s -> s_all[0] L1-hit broadcast); single select on j<cnt.
// Tie-break matches jax.lax.top_k (equal value -> lower index):
// key = (score_bits<<32)|(63-j); valid scores exp(...) > 0 so zeroed score
// bits are a safe knockout.
__global__ __launch_bounds__(256) void ns_topk_kernel(
    const int* __restrict__ neighbors, // (N, 64) int32
    const int* __restrict__ counts,    // (N,)    int32
    const float* __restrict__ s_self,  // (N,)
    const float* __restrict__ s_all,   // (N,)
    float* __restrict__ out_vals,      // (N, 3)
    float* __restrict__ out_idx,       // (N, 3)  indices as float
    int N)
{
    const int wave = (blockIdx.x * blockDim.x + threadIdx.x) >> 6;
    const int lane = threadIdx.x & 63;
    const int sub  = lane >> 4;
    const int p    = lane & 15;
    const int row  = wave * 4 + sub;
    if (row >= N) return;

    const int   cnt = counts[row];     // uniform in team -> broadcast line
    const float ss  = s_self[row];

    v4i nb = (v4i){0, 0, 0, 0};
    if (p * 4 < cnt) {                 // skip fully-masked int4s entirely
        nb = __builtin_nontemporal_load(
            (const v4i*)(neighbors + (size_t)row * M_DIM) + p);
    }

    const int nbs[4] = { nb.x, nb.y, nb.z, nb.w };
    u64 key[4];
    #pragma unroll
    for (int e = 0; e < 4; ++e) {
        const int j = p * 4 + e;
        const float x  = ss + s_all[nbs[e]];       // L2-resident gather
        const float lr = (x >= 0.0f) ? x : 0.01f * x;
        const float sc = expf(lr);                 // finite for all inputs
        const float score = (j < cnt) ? sc : 0.0f; // select, not branch
        key[e] = ((u64)__float_as_uint(score) << 32) | (u64)(63 - j);
    }

    float vals[K_TOP];
    int   idxs[K_TOP];

    #pragma unroll
    for (int k = 0; k < K_TOP; ++k) {
        u64 m = key[0];
        if (key[1] > m) m = key[1];
        if (key[2] > m) m = key[2];
        if (key[3] > m) m = key[3];
        #pragma unroll
        for (int off = 8; off > 0; off >>= 1) {
            const u64 o = __shfl_xor(m, off);
            if (o > m) m = o;
        }
        const int jwin = 63 - (int)(m & 0x3F);
        vals[k] = __uint_as_float((unsigned)(m >> 32));

        const int ew = jwin & 3;       // element within owner's int4
        const int pw = jwin >> 2;      // owner lane within team
        const int cand = (ew == 0) ? nbs[0] : (ew == 1) ? nbs[1]
                       : (ew == 2) ? nbs[2] : nbs[3];
        idxs[k] = __shfl(cand, (sub << 4) | pw);   // owner was active (jwin<cnt)

        if (p == pw) {                 // owner knocks out the winning element
            const u64 dead = (u64)(63 - jwin);
            if      (ew == 0) key[0] = dead;
            else if (ew == 1) key[1] = dead;
            else if (ew == 2) key[2] = dead;
            else              key[3] = dead;
        }
    }

    if (p == 0) {
        const size_t base = (size_t)row * K_TOP;
        #pragma unroll
        for (int k = 0; k < K_TOP; ++k) {
            out_vals[base + k] = vals[k];
            out_idx [base + k] = (float)idxs[k];
        }
    }
}

extern "C" void kernel_launch(void* const* d_in, const int* in_sizes, int n_in,
                              void* d_out, int out_size, void* d_ws, size_t ws_size,
                              hipStream_t stream)
{
    const float* nf        = (const float*)d_in[0];   // (N, 256)
    const int*   neighbors = (const int*)  d_in[1];   // (N, 64)
    const int*   counts    = (const int*)  d_in[2];   // (N,)
    const float* W         = (const float*)d_in[3];   // (512,)
    const float* b         = (const float*)d_in[4];   // (1,)

    const int N = in_sizes[2];

    float* s_self = (float*)d_ws;                     // N floats
    float* s_all  = s_self + N;                       // N floats

    float* out_vals = (float*)d_out;                  // N*3
    float* out_idx  = out_vals + (size_t)N * K_TOP;   // N*3 (indices as float)

    const int threads = 256;                          // 4 waves -> 16 rows/block
    const int rowsPerBlock = (threads / 64) * 4;
    const int blocks = (N + rowsPerBlock - 1) / rowsPerBlock;

    ns_scores_kernel<<<blocks, threads, 0, stream>>>(nf, W, b, s_self, s_all, N);
    ns_topk_kernel<<<blocks, threads, 0, stream>>>(neighbors, counts, s_self, s_all,
                                                   out_vals, out_idx, N);
}